// Round 18
// baseline (214.567 us; speedup 1.0000x reference)
//
#include <hip/hip_runtime.h>
#include <hip/hip_bf16.h>
#include <hip/hip_fp8.h>
#include <stdint.h>

#define B_ROWS 1024
#define DIM    512
#define C_CLS  100000
#define C_PAD  100352          // 8 XCDs * 98 ntiles * 128
#define NT     784             // C_PAD / 128
#define NT_PER_XCD 98
#define NPAD   (C_PAD - C_CLS) // 352 pad cols, logit 0

using f32x4 = __attribute__((ext_vector_type(4))) float;
using i32x4 = __attribute__((ext_vector_type(4))) int;
using i32x8 = __attribute__((ext_vector_type(8))) int;

#define AS1(p) ((const __attribute__((address_space(1))) uint32_t*)(p))
#define AS3(p) ((__attribute__((address_space(3))) uint32_t*)(p))
#define SBAR()   __builtin_amdgcn_s_barrier()
#define SCHED0() __builtin_amdgcn_sched_barrier(0)
#define LGKM0()  asm volatile("s_waitcnt lgkmcnt(0)" ::: "memory")
#define VMCNT0() asm volatile("s_waitcnt vmcnt(0)" ::: "memory")

static __device__ __forceinline__ uint32_t f2fp8(float f) {
    __hip_fp8_e4m3 q(f);
    return (uint32_t)q.__x;
}

// ---------- pass 1 (features only): per-row L2 normalize, f32 -> fp8 e4m3
__global__ __launch_bounds__(256) void normalize_rows(
    const float* __restrict__ src, uint8_t* __restrict__ dst)
{
    const int row  = blockIdx.x * 4 + (threadIdx.x >> 6);
    const int lane = threadIdx.x & 63;
    uint2* d2 = reinterpret_cast<uint2*>(dst + (size_t)row * DIM);    // 8 B per lane
    const float4* s4 = reinterpret_cast<const float4*>(src + (size_t)row * DIM);
    const float4 a = s4[lane * 2], b = s4[lane * 2 + 1];
    float ss = a.x*a.x + a.y*a.y + a.z*a.z + a.w*a.w
             + b.x*b.x + b.y*b.y + b.z*b.z + b.w*b.w;
    #pragma unroll
    for (int k = 1; k < 64; k <<= 1) ss += __shfl_xor(ss, k);
    const float inv = 1.0f / fmaxf(sqrtf(ss), 1e-12f);
    uint2 o;
    o.x = f2fp8(a.x*inv) | (f2fp8(a.y*inv) << 8) | (f2fp8(a.z*inv) << 16) | (f2fp8(a.w*inv) << 24);
    o.y = f2fp8(b.x*inv) | (f2fp8(b.y*inv) << 8) | (f2fp8(b.z*inv) << 16) | (f2fp8(b.w*inv) << 24);
    d2[lane] = o;
}

// ---------- pass 2: FUSED normalize-W + GEMM. One block per ntile.
//   phase 1: W tile [128][512] f32 -> fp8 normalized, written swizzled into LDS (64 KiB)
//   phase 2: 8 mtile passes vs resident W; A staged per kt (16 KiB, r14-proven ledger)
__global__ __launch_bounds__(256, 2) void gemm_fused(
    const uint8_t* __restrict__ A,    // [B_ROWS][DIM] fp8 normalized features
    const float*   __restrict__ Wsrc, // [C_CLS][DIM]  raw f32 weights
    float* __restrict__ ps)           // [NT][B_ROWS]
{
    __shared__ __align__(16) uint8_t ldsW[128 * 512];   // 64 KiB resident W tile (fp8)
    __shared__ __align__(16) uint8_t ldsA[128 * 128];   // 16 KiB A k-tile / red buffer

    const int tid  = threadIdx.x;
    const int lane = tid & 63;
    const int wid  = tid >> 6;       // 4 waves, 2x2: each owns 64x64 of a 128x128 output
    const int wm   = wid >> 1;
    const int wn   = wid & 1;

    const int b     = blockIdx.x;    // 0..783
    const int ntile = (b & 7) * NT_PER_XCD + (b >> 3);

    // ======== phase 1: normalize W tile into ldsW (swizzled, row stride 512) ========
    // wave wid owns rows wid*32 .. +32; lane covers k-bytes [lane*8, lane*8+8)
    {
        const int kt_w  = lane >> 4;              // k-segment 0..3 (128B each)
        const int unit  = (lane & 15) >> 1;       // 16B unit within segment
        const int half8 = (lane & 1) * 8;
        #pragma unroll 1
        for (int g = 0; g < 32; g += 8) {
            float4 va[8], vb[8];
            #pragma unroll
            for (int i = 0; i < 8; ++i) {
                const int grow = ntile * 128 + wid * 32 + g + i;
                if (grow < C_CLS) {
                    const float4* p = reinterpret_cast<const float4*>(Wsrc + (size_t)grow * DIM) + lane * 2;
                    va[i] = p[0]; vb[i] = p[1];
                } else {
                    va[i] = make_float4(0.f, 0.f, 0.f, 0.f);
                    vb[i] = make_float4(0.f, 0.f, 0.f, 0.f);
                }
            }
            #pragma unroll
            for (int i = 0; i < 8; ++i) {
                const int r = wid * 32 + g + i;
                float ss = va[i].x*va[i].x + va[i].y*va[i].y + va[i].z*va[i].z + va[i].w*va[i].w
                         + vb[i].x*vb[i].x + vb[i].y*vb[i].y + vb[i].z*vb[i].z + vb[i].w*vb[i].w;
                #pragma unroll
                for (int k = 1; k < 64; k <<= 1) ss += __shfl_xor(ss, k);
                const float inv = 1.0f / fmaxf(sqrtf(ss), 1e-12f);
                uint2 o;
                o.x = f2fp8(va[i].x*inv) | (f2fp8(va[i].y*inv) << 8)
                    | (f2fp8(va[i].z*inv) << 16) | (f2fp8(va[i].w*inv) << 24);
                o.y = f2fp8(vb[i].x*inv) | (f2fp8(vb[i].y*inv) << 8)
                    | (f2fp8(vb[i].z*inv) << 16) | (f2fp8(vb[i].w*inv) << 24);
                *reinterpret_cast<uint2*>(
                    &ldsW[r * 512 + kt_w * 128 + ((unit ^ (r & 7)) << 4) + half8]) = o;
            }
        }
    }
    __syncthreads();                 // W tile visible to all waves

    // ======== phase 2: 8 mtile passes ========
    auto stageA = [&](int mt, int kt) {
        #pragma unroll
        for (int p = 0; p < 4; ++p) {
            const int u   = tid + p * 256;
            const int row = u >> 3;
            const int sub = (u & 7) ^ (row & 7);
            const uint8_t* As = A + ((size_t)(mt * 128 + row)) * DIM + kt * 128 + sub * 16;
            __builtin_amdgcn_global_load_lds(AS1(As), AS3(&ldsA[u * 16]), 16, 0, 0);
        }
    };

    const int l15 = lane & 15;
    const int uhi = lane >> 4;       // k-quarter: lane holds k = uhi*32 .. +32

    auto ldAf = [&](int mi) -> i32x8 {
        const int row = wm * 64 + mi * 16 + l15;
        const int swz = row & 7;
        const i32x4 lo = *reinterpret_cast<const i32x4*>(&ldsA[row * 128 + (((uhi << 1) | 0) ^ swz) * 16]);
        const i32x4 hi = *reinterpret_cast<const i32x4*>(&ldsA[row * 128 + (((uhi << 1) | 1) ^ swz) * 16]);
        i32x8 r; r[0]=lo[0]; r[1]=lo[1]; r[2]=lo[2]; r[3]=lo[3];
                 r[4]=hi[0]; r[5]=hi[1]; r[6]=hi[2]; r[7]=hi[3];
        return r;
    };
    auto ldBf = [&](int kt, int ni) -> i32x8 {
        const int row = wn * 64 + ni * 16 + l15;
        const int swz = row & 7;
        const uint8_t* base = &ldsW[row * 512 + kt * 128];
        const i32x4 lo = *reinterpret_cast<const i32x4*>(base + ((((uhi << 1) | 0) ^ swz) << 4));
        const i32x4 hi = *reinterpret_cast<const i32x4*>(base + ((((uhi << 1) | 1) ^ swz) << 4));
        i32x8 r; r[0]=lo[0]; r[1]=lo[1]; r[2]=lo[2]; r[3]=lo[3];
                 r[4]=hi[0]; r[5]=hi[1]; r[6]=hi[2]; r[7]=hi[3];
        return r;
    };

    i32x8 aF[4], bF[4];

    stageA(0, 0);                    // prologue

    #pragma unroll 1
    for (int mt = 0; mt < 8; ++mt) {
        f32x4 acc[4][4] = {};
        #pragma unroll
        for (int kt = 0; kt < 4; ++kt) {
            VMCNT0(); SBAR();                 // A tile (mt,kt) landed for all waves
            #pragma unroll
            for (int mi = 0; mi < 4; ++mi) aF[mi] = ldAf(mi);
            #pragma unroll
            for (int ni = 0; ni < 4; ++ni) bF[ni] = ldBf(kt, ni);
            LGKM0(); SCHED0(); SBAR();        // all waves' A reads retired
            if (kt < 3) stageA(mt, kt + 1);   // flies under MFMA phase
            #pragma unroll
            for (int mi = 0; mi < 4; ++mi)
                #pragma unroll
                for (int ni = 0; ni < 4; ++ni)
                    acc[mi][ni] = __builtin_amdgcn_mfma_scale_f32_16x16x128_f8f6f4(
                        aF[mi], bF[ni], acc[mi][ni], 0, 0, 0, 127, 0, 127);
        }
        // epilogue for mt: fixed-shift sumexp over this 128x128; red buffer = ldsA
        float* red = reinterpret_cast<float*>(&ldsA[0]);    // [128 rows][2 wn]
        #pragma unroll
        for (int mi = 0; mi < 4; ++mi) {
            #pragma unroll
            for (int r = 0; r < 4; ++r) {
                float s = __expf(fmaf(acc[mi][0][r], 64.0f, -64.0f))
                        + __expf(fmaf(acc[mi][1][r], 64.0f, -64.0f))
                        + __expf(fmaf(acc[mi][2][r], 64.0f, -64.0f))
                        + __expf(fmaf(acc[mi][3][r], 64.0f, -64.0f));
                #pragma unroll
                for (int k = 1; k < 16; k <<= 1) s += __shfl_xor(s, k);
                if (l15 == 0) red[(wm * 64 + mi * 16 + uhi * 4 + r) * 2 + wn] = s;
            }
        }
        __syncthreads();
        if (tid < 128)
            ps[(size_t)ntile * B_ROWS + mt * 128 + tid] = red[tid * 2] + red[tid * 2 + 1];
        __syncthreads();                      // red reads done -> ldsA reusable
        if (mt < 7) stageA(mt + 1, 0);
    }
}

// ---------- pass 3: per-row sum of partials + exact (f32) margin/pad correction
__global__ __launch_bounds__(256) void finalize(
    const float* __restrict__ ps,
    const float* __restrict__ features, const float* __restrict__ weight,
    const int* __restrict__ labels, float* __restrict__ row_loss)
{
    const int row = blockIdx.x;
    const int t   = threadIdx.x;      // 256
    const int lab = labels[row];

    // target cosine in full f32 (exact dominant term; fp8 noise stays only in logZ)
    const float2 f2 = reinterpret_cast<const float2*>(features + (size_t)row * DIM)[t];
    const float2 w2 = reinterpret_cast<const float2*>(weight + (size_t)lab * DIM)[t];
    float d  = f2.x * w2.x + f2.y * w2.y;
    float nf = f2.x * f2.x + f2.y * f2.y;
    float nw = w2.x * w2.x + w2.y * w2.y;
    #pragma unroll
    for (int k = 1; k < 64; k <<= 1) {
        d += __shfl_xor(d, k); nf += __shfl_xor(nf, k); nw += __shfl_xor(nw, k);
    }

    float s = 0.0f;
    for (int i = t; i < NT; i += 256) s += ps[(size_t)i * B_ROWS + row];
    #pragma unroll
    for (int k = 1; k < 64; k <<= 1) s += __shfl_xor(s, k);

    __shared__ float sd[4], sf[4], sw[4], ssm[4];
    if ((t & 63) == 0) { sd[t>>6] = d; sf[t>>6] = nf; sw[t>>6] = nw; ssm[t>>6] = s; }
    __syncthreads();
    if (t == 0) {
        const float dt = sd[0] + sd[1] + sd[2] + sd[3];
        const float nft = sf[0] + sf[1] + sf[2] + sf[3];
        const float nwt = sw[0] + sw[1] + sw[2] + sw[3];
        float S = ssm[0] + ssm[1] + ssm[2] + ssm[3];
        const float cosv = dt / (fmaxf(sqrtf(nft), 1e-12f) * fmaxf(sqrtf(nwt), 1e-12f));
        const float lt = 64.0f * cosv;
        // swap unmargined target term for margined one; remove pad columns (logit 0)
        S += expf(lt - 96.0f) - expf(lt - 64.0f) - (float)NPAD * expf(-64.0f);
        row_loss[row] = 64.0f + logf(S) - (lt - 32.0f);
    }
}

// ---------- pass 4: mean over rows
__global__ __launch_bounds__(256) void mean_k(const float* __restrict__ rl, float* __restrict__ out)
{
    const int t = threadIdx.x;
    float s = 0.0f;
    for (int i = t; i < B_ROWS; i += 256) s += rl[i];
    #pragma unroll
    for (int k = 1; k < 64; k <<= 1) s += __shfl_xor(s, k);
    __shared__ float r4[4];
    if ((t & 63) == 0) r4[t >> 6] = s;
    __syncthreads();
    if (t == 0) out[0] = (r4[0] + r4[1] + r4[2] + r4[3]) * (1.0f / B_ROWS);
}

extern "C" void kernel_launch(void* const* d_in, const int* in_sizes, int n_in,
                              void* d_out, int out_size, void* d_ws, size_t ws_size,
                              hipStream_t stream)
{
    const float* features = (const float*)d_in[0];
    const int*   labels   = (const int*)d_in[1];
    const float* weight   = (const float*)d_in[2];

    char* ws = (char*)d_ws;
    uint8_t* fb   = (uint8_t*)ws;                                        // B_ROWS * DIM fp8
    float*   psum = (float*)(ws + (size_t)B_ROWS * DIM);
    float*   rl   = psum + (size_t)NT * B_ROWS;

    normalize_rows<<<B_ROWS / 4, 256, 0, stream>>>(features, fb);
    gemm_fused<<<NT, 256, 0, stream>>>(fb, weight, psum);
    finalize<<<B_ROWS, 256, 0, stream>>>(psum, features, weight, labels, rl);
    mean_k<<<1, 256, 0, stream>>>(rl, (float*)d_out);
}

// Round 19
// 167.005 us; speedup vs baseline: 1.2848x; 1.2848x over previous
//
#include <hip/hip_runtime.h>
#include <hip/hip_bf16.h>
#include <hip/hip_fp8.h>
#include <stdint.h>

#define B_ROWS 1024
#define DIM    512
#define C_CLS  100000
#define C_PAD  100352          // 8 XCDs * 98 ntiles * 128
#define NT     784             // C_PAD / 128
#define NT_PER_XCD 98
#define MT     8               // B_ROWS / 128
#define NPAD   (C_PAD - C_CLS) // 352 pad cols, logit 0

using f32x4 = __attribute__((ext_vector_type(4))) float;
using i32x4 = __attribute__((ext_vector_type(4))) int;
using i32x8 = __attribute__((ext_vector_type(8))) int;

#define AS1(p) ((const __attribute__((address_space(1))) uint32_t*)(p))
#define AS3(p) ((__attribute__((address_space(3))) uint32_t*)(p))
#define SCHED0() __builtin_amdgcn_sched_barrier(0)
#define LGKM0()  asm volatile("s_waitcnt lgkmcnt(0)" ::: "memory")
#define VMCNT0() asm volatile("s_waitcnt vmcnt(0)" ::: "memory")

static __device__ __forceinline__ uint32_t f2fp8(float f) {
    __hip_fp8_e4m3 q(f);
    return (uint32_t)q.__x;
}
static __device__ __forceinline__ float fp82f(uint32_t b) {
    __hip_fp8_e4m3 h;
    h.__x = (__hip_fp8_storage_t)b;
    return (float)h;
}

// ---------- pass 1: per-row L2 normalize (one wave per row), f32 -> fp8 e4m3; pad rows zeroed
__global__ __launch_bounds__(256) void normalize_rows(
    const float* __restrict__ src, uint8_t* __restrict__ dst, int nvalid, int ntotal)
{
    const int row  = blockIdx.x * 4 + (threadIdx.x >> 6);
    const int lane = threadIdx.x & 63;
    if (row >= ntotal) return;
    uint2* d2 = reinterpret_cast<uint2*>(dst + (size_t)row * DIM);    // 8 B per lane
    if (row >= nvalid) { d2[lane] = make_uint2(0u, 0u); return; }
    const float4* s4 = reinterpret_cast<const float4*>(src + (size_t)row * DIM);
    const float4 a = s4[lane * 2], b = s4[lane * 2 + 1];
    float ss = a.x*a.x + a.y*a.y + a.z*a.z + a.w*a.w
             + b.x*b.x + b.y*b.y + b.z*b.z + b.w*b.w;
    #pragma unroll
    for (int k = 1; k < 64; k <<= 1) ss += __shfl_xor(ss, k);
    const float inv = 1.0f / fmaxf(sqrtf(ss), 1e-12f);
    uint2 o;
    o.x = f2fp8(a.x*inv) | (f2fp8(a.y*inv) << 8) | (f2fp8(a.z*inv) << 16) | (f2fp8(a.w*inv) << 24);
    o.y = f2fp8(b.x*inv) | (f2fp8(b.y*inv) << 8) | (f2fp8(b.z*inv) << 16) | (f2fp8(b.w*inv) << 24);
    d2[lane] = o;
}

// ---------- pass 2: 128x128 MX-fp8 MFMA; WAVE-PRIVATE staging -> ZERO barriers in k-loop.
//            Each wave stages its own A-half + B-half (16 KiB private region); all sync is
//            wave-local (VMCNT0 = own loads, LGKM0 = own reads) -> waves self-pace, no convoy.
__global__ __launch_bounds__(256) void gemm_lse(
    const uint8_t* __restrict__ A,    // [B_ROWS][DIM]  fp8
    const uint8_t* __restrict__ W,    // [C_PAD][DIM]   fp8 (pad rows zero)
    float* __restrict__ ps)           // [NT][B_ROWS]
{
    // [wave][region: 0=A-half, 1=B-half][64 rows * 128 k fp8 = 8 KiB] = 64 KiB
    __shared__ __align__(16) uint8_t lds[4][2][64 * 128];

    const int tid  = threadIdx.x;
    const int lane = tid & 63;
    const int wid  = tid >> 6;       // 4 waves, 2x2: each owns 64x64
    const int wm   = wid >> 1;
    const int wn   = wid & 1;

    const int b     = blockIdx.x;
    const int xcd   = b & 7;
    const int j     = b >> 3;        // 0..783 within XCD
    const int ntile = xcd * NT_PER_XCD + (j >> 3);
    const int mtile = j & 7;

    // wave-private source bases: A rows wm*64.., W rows wn*64..
    const uint8_t* Asrc = A + ((size_t)(mtile * 128 + wm * 64)) * DIM;
    const uint8_t* Bsrc = W + ((size_t)(ntile * 128 + wn * 64)) * DIM;

    // wave stages its 2 regions: 512 16B-units each; lane covers u = lane + i*64.
    // unit u: row = u>>3 (0..63), sub = (u&7)^(row&7) (inverse-swizzled source, rule #21)
    auto stage = [&](int kt) {
        #pragma unroll
        for (int i = 0; i < 8; ++i) {
            const int u   = lane + i * 64;
            const int row = u >> 3;
            const int sub = (u & 7) ^ (row & 7);
            __builtin_amdgcn_global_load_lds(
                AS1(Asrc + (size_t)row * DIM + kt * 128 + sub * 16),
                AS3(&lds[wid][0][u * 16]), 16, 0, 0);
            __builtin_amdgcn_global_load_lds(
                AS1(Bsrc + (size_t)row * DIM + kt * 128 + sub * 16),
                AS3(&lds[wid][1][u * 16]), 16, 0, 0);
        }
    };

    const int l15 = lane & 15;
    const int uhi = lane >> 4;       // k-quarter: lane holds k = uhi*32 .. +32

    i32x8 aF[4], bF[4];
    f32x4 acc[4][4] = {};

    auto ldfrag = [&](int reg, int r) -> i32x8 {   // r = local row 0..63
        const int swz = r & 7;
        const uint8_t* base = &lds[wid][reg][0];
        const i32x4 lo = *reinterpret_cast<const i32x4*>(base + r * 128 + (((uhi << 1) | 0) ^ swz) * 16);
        const i32x4 hi = *reinterpret_cast<const i32x4*>(base + r * 128 + (((uhi << 1) | 1) ^ swz) * 16);
        i32x8 v; v[0]=lo[0]; v[1]=lo[1]; v[2]=lo[2]; v[3]=lo[3];
                 v[4]=hi[0]; v[5]=hi[1]; v[6]=hi[2]; v[7]=hi[3];
        return v;
    };

    stage(0);                        // prologue (wave-local)

    #pragma unroll 1
    for (int kt = 0; kt < 4; ++kt) {
        VMCNT0(); SCHED0();               // own 16 loads of tile kt landed
        #pragma unroll
        for (int mi = 0; mi < 4; ++mi) aF[mi] = ldfrag(0, mi * 16 + l15);
        #pragma unroll
        for (int ni = 0; ni < 4; ++ni) bF[ni] = ldfrag(1, ni * 16 + l15);
        LGKM0(); SCHED0();                // own reads retired -> region reusable
        if (kt < 3) stage(kt + 1);        // flies under the MFMAs below
        #pragma unroll
        for (int mi = 0; mi < 4; ++mi)
            #pragma unroll
            for (int ni = 0; ni < 4; ++ni)
                acc[mi][ni] = __builtin_amdgcn_mfma_scale_f32_16x16x128_f8f6f4(
                    aF[mi], bF[ni], acc[mi][ni], 0, 0, 0, 127, 0, 127);
    }

    // epilogue: logits = 64*cos in [-64,64]; fixed shift 64 -> sum exp(logit-64)
    __syncthreads();                               // all waves done; reuse LDS as red buffer
    float* red = reinterpret_cast<float*>(&lds[0][0][0]);   // [128 rows][2 wn]
    #pragma unroll
    for (int mi = 0; mi < 4; ++mi) {
        #pragma unroll
        for (int r = 0; r < 4; ++r) {
            float s = __expf(fmaf(acc[mi][0][r], 64.0f, -64.0f))
                    + __expf(fmaf(acc[mi][1][r], 64.0f, -64.0f))
                    + __expf(fmaf(acc[mi][2][r], 64.0f, -64.0f))
                    + __expf(fmaf(acc[mi][3][r], 64.0f, -64.0f));
            #pragma unroll
            for (int k = 1; k < 16; k <<= 1) s += __shfl_xor(s, k);
            if (l15 == 0) red[(wm * 64 + mi * 16 + uhi * 4 + r) * 2 + wn] = s;
        }
    }
    __syncthreads();
    if (tid < 128)
        ps[(size_t)ntile * B_ROWS + mtile * 128 + tid] = red[tid * 2] + red[tid * 2 + 1];
}

// ---------- pass 3: per-row sum of partials + exact margin/pad correction
__global__ __launch_bounds__(256) void finalize(
    const float* __restrict__ ps,
    const uint8_t* __restrict__ fb, const uint8_t* __restrict__ wb,
    const int* __restrict__ labels, float* __restrict__ row_loss)
{
    const int row = blockIdx.x;
    const int t   = threadIdx.x;      // 256
    const int lab = labels[row];

    // target logit from the SAME fp8 values the GEMM consumed (consistent cancellation)
    const uint8_t* frow = fb + (size_t)row * DIM;
    const uint8_t* wrow = wb + (size_t)lab * DIM;
    uint32_t fa = *reinterpret_cast<const uint16_t*>(frow + 2 * t);
    uint32_t wa = *reinterpret_cast<const uint16_t*>(wrow + 2 * t);
    float d = fp82f(fa & 0xffu) * fp82f(wa & 0xffu)
            + fp82f(fa >> 8)    * fp82f(wa >> 8);
    #pragma unroll
    for (int k = 1; k < 64; k <<= 1) d += __shfl_xor(d, k);

    float s = 0.0f;
    for (int i = t; i < NT; i += 256) s += ps[(size_t)i * B_ROWS + row];
    #pragma unroll
    for (int k = 1; k < 64; k <<= 1) s += __shfl_xor(s, k);

    __shared__ float sd[4], ssm[4];
    if ((t & 63) == 0) { sd[t >> 6] = d; ssm[t >> 6] = s; }
    __syncthreads();
    if (t == 0) {
        const float dt = sd[0] + sd[1] + sd[2] + sd[3];
        float S = ssm[0] + ssm[1] + ssm[2] + ssm[3];
        const float lt = 64.0f * dt;
        // swap unmargined target term for margined one; remove pad columns (logit 0)
        S += expf(lt - 96.0f) - expf(lt - 64.0f) - (float)NPAD * expf(-64.0f);
        row_loss[row] = 64.0f + logf(S) - (lt - 32.0f);
    }
}

// ---------- pass 4: mean over rows
__global__ __launch_bounds__(256) void mean_k(const float* __restrict__ rl, float* __restrict__ out)
{
    const int t = threadIdx.x;
    float s = 0.0f;
    for (int i = t; i < B_ROWS; i += 256) s += rl[i];
    #pragma unroll
    for (int k = 1; k < 64; k <<= 1) s += __shfl_xor(s, k);
    __shared__ float r4[4];
    if ((t & 63) == 0) r4[t >> 6] = s;
    __syncthreads();
    if (t == 0) out[0] = (r4[0] + r4[1] + r4[2] + r4[3]) * (1.0f / B_ROWS);
}

extern "C" void kernel_launch(void* const* d_in, const int* in_sizes, int n_in,
                              void* d_out, int out_size, void* d_ws, size_t ws_size,
                              hipStream_t stream)
{
    const float* features = (const float*)d_in[0];
    const int*   labels   = (const int*)d_in[1];
    const float* weight   = (const float*)d_in[2];

    char* ws = (char*)d_ws;
    uint8_t* wb = (uint8_t*)ws;                                          // C_PAD * DIM fp8
    uint8_t* fb = (uint8_t*)(ws + (size_t)C_PAD * DIM);                  // B_ROWS * DIM fp8
    float*   psum = (float*)(ws + (size_t)C_PAD * DIM + (size_t)B_ROWS * DIM);
    float*   rl = psum + (size_t)NT * B_ROWS;

    normalize_rows<<<C_PAD / 4, 256, 0, stream>>>(weight, wb, C_CLS, C_PAD);
    normalize_rows<<<B_ROWS / 4, 256, 0, stream>>>(features, fb, B_ROWS, B_ROWS);
    gemm_lse<<<NT * MT, 256, 0, stream>>>(fb, wb, psum);
    finalize<<<B_ROWS, 256, 0, stream>>>(psum, fb, wb, labels, rl);
    mean_k<<<1, 256, 0, stream>>>(rl, (float*)d_out);
}

// Round 20
// 130.148 us; speedup vs baseline: 1.6486x; 1.2832x over previous
//
#include <hip/hip_runtime.h>
#include <hip/hip_bf16.h>
#include <hip/hip_fp8.h>
#include <stdint.h>

#define B_ROWS 1024
#define DIM    512
#define C_CLS  100000
#define C_PAD  100352          // 8 XCDs * 98 ntiles * 128
#define NT     784             // C_PAD / 128
#define NT_PER_XCD 98
#define MT     8               // B_ROWS / 128
#define NPAD   (C_PAD - C_CLS) // 352 pad cols, logit 0

using f32x4 = __attribute__((ext_vector_type(4))) float;
using i32x4 = __attribute__((ext_vector_type(4))) int;
using i32x8 = __attribute__((ext_vector_type(8))) int;

#define AS1(p) ((const __attribute__((address_space(1))) uint32_t*)(p))
#define AS3(p) ((__attribute__((address_space(3))) uint32_t*)(p))
#define SBAR()   __builtin_amdgcn_s_barrier()
#define VMCNT0() asm volatile("s_waitcnt vmcnt(0)" ::: "memory")

static __device__ __forceinline__ uint32_t f2fp8(float f) {
    __hip_fp8_e4m3 q(f);
    return (uint32_t)q.__x;
}
static __device__ __forceinline__ float fp82f(uint32_t b) {
    __hip_fp8_e4m3 h;
    h.__x = (__hip_fp8_storage_t)b;
    return (float)h;
}

// ---------- pass 1: per-row L2 normalize (one wave per row), f32 -> fp8 e4m3; pad rows zeroed
__global__ __launch_bounds__(256) void normalize_rows(
    const float* __restrict__ src, uint8_t* __restrict__ dst, int nvalid, int ntotal)
{
    const int row  = blockIdx.x * 4 + (threadIdx.x >> 6);
    const int lane = threadIdx.x & 63;
    if (row >= ntotal) return;
    uint2* d2 = reinterpret_cast<uint2*>(dst + (size_t)row * DIM);    // 8 B per lane
    if (row >= nvalid) { d2[lane] = make_uint2(0u, 0u); return; }
    const float4* s4 = reinterpret_cast<const float4*>(src + (size_t)row * DIM);
    const float4 a = s4[lane * 2], b = s4[lane * 2 + 1];
    float ss = a.x*a.x + a.y*a.y + a.z*a.z + a.w*a.w
             + b.x*b.x + b.y*b.y + b.z*b.z + b.w*b.w;
    #pragma unroll
    for (int k = 1; k < 64; k <<= 1) ss += __shfl_xor(ss, k);
    const float inv = 1.0f / fmaxf(sqrtf(ss), 1e-12f);
    uint2 o;
    o.x = f2fp8(a.x*inv) | (f2fp8(a.y*inv) << 8) | (f2fp8(a.z*inv) << 16) | (f2fp8(a.w*inv) << 24);
    o.y = f2fp8(b.x*inv) | (f2fp8(b.y*inv) << 8) | (f2fp8(b.z*inv) << 16) | (f2fp8(b.w*inv) << 24);
    d2[lane] = o;
}

// ---------- pass 2: 128x128 MX-fp8 MFMA (K=128, unit E8M0 scales -> exact fp8 math at 2x rate),
//            m97 structure: 4 waves, single 32KiB LDS buffer, high TLP.  [champion, r14]
__global__ __launch_bounds__(256, 3) void gemm_lse(
    const uint8_t* __restrict__ A,    // [B_ROWS][DIM]  fp8
    const uint8_t* __restrict__ W,    // [C_PAD][DIM]   fp8 (pad rows zero)
    float* __restrict__ ps)           // [NT][B_ROWS]
{
    // [region: 0=A, 1=B][128 rows * 128 k fp8 = 16384 B], 32 KiB single buffer
    __shared__ __align__(16) uint8_t lds[2][128 * 128];

    const int tid  = threadIdx.x;
    const int lane = tid & 63;
    const int wid  = tid >> 6;       // 4 waves, 2x2: each owns 64x64
    const int wm   = wid >> 1;
    const int wn   = wid & 1;

    const int b     = blockIdx.x;
    const int xcd   = b & 7;
    const int j     = b >> 3;        // 0..783 within XCD
    const int ntile = xcd * NT_PER_XCD + (j >> 3);
    const int mtile = j & 7;

    const uint8_t* Abase = A + (size_t)mtile * 128 * DIM;
    const uint8_t* Bbase = W + (size_t)ntile * 128 * DIM;

    // staging: per region 1024 16B units (row = u>>3, 16B-sub = u&7); source sub
    // pre-swizzled by row&7 (both-sides XOR, 16B granularity -> contiguous source).
    auto stage = [&](int kt) {
        #pragma unroll
        for (int p = 0; p < 4; ++p) {
            const int u   = tid + p * 256;
            const int row = u >> 3;
            const int sub = (u & 7) ^ (row & 7);
            const uint8_t* As = Abase + (size_t)row * DIM + kt * 128 + sub * 16;
            const uint8_t* Bs = Bbase + (size_t)row * DIM + kt * 128 + sub * 16;
            __builtin_amdgcn_global_load_lds(AS1(As), AS3(&lds[0][u * 16]), 16, 0, 0);
            __builtin_amdgcn_global_load_lds(AS1(Bs), AS3(&lds[1][u * 16]), 16, 0, 0);
        }
    };

    const int l15 = lane & 15;
    const int uhi = lane >> 4;       // k-quarter: lane holds k = uhi*32 .. +32

    i32x8 aF[4], bF[4];
    f32x4 acc[4][4] = {};

    auto ldfrag = [&](const uint8_t* base, int row) -> i32x8 {
        const int swz = row & 7;
        const i32x4 lo = *reinterpret_cast<const i32x4*>(base + row * 128 + (((uhi << 1) | 0) ^ swz) * 16);
        const i32x4 hi = *reinterpret_cast<const i32x4*>(base + row * 128 + (((uhi << 1) | 1) ^ swz) * 16);
        i32x8 r;
        r[0] = lo[0]; r[1] = lo[1]; r[2] = lo[2]; r[3] = lo[3];
        r[4] = hi[0]; r[5] = hi[1]; r[6] = hi[2]; r[7] = hi[3];
        return r;
    };

    // prologue
    stage(0);

    #pragma unroll 1
    for (int kt = 0; kt < 4; ++kt) {
        VMCNT0(); SBAR();                 // tile kt landed for all waves
        #pragma unroll
        for (int mi = 0; mi < 4; ++mi) aF[mi] = ldfrag(&lds[0][0], wm * 64 + mi * 16 + l15);
        #pragma unroll
        for (int ni = 0; ni < 4; ++ni) bF[ni] = ldfrag(&lds[1][0], wn * 64 + ni * 16 + l15);
        #pragma unroll
        for (int mi = 0; mi < 4; ++mi)
            #pragma unroll
            for (int ni = 0; ni < 4; ++ni)
                acc[mi][ni] = __builtin_amdgcn_mfma_scale_f32_16x16x128_f8f6f4(
                    aF[mi], bF[ni], acc[mi][ni], 0, 0, 0, 127, 0, 127);
        SBAR();                           // all waves' reads retired -> overwrite safe
        if (kt < 3) stage(kt + 1);
    }

    // epilogue: logits = 64*cos in [-64,64]; fixed shift 64 -> sum exp(logit-64)
    __syncthreads();                               // full drain; reuse LDS as red buffer
    float* red = reinterpret_cast<float*>(&lds[0][0]);      // [128 rows][2 wn]
    #pragma unroll
    for (int mi = 0; mi < 4; ++mi) {
        #pragma unroll
        for (int r = 0; r < 4; ++r) {
            float s = __expf(fmaf(acc[mi][0][r], 64.0f, -64.0f))
                    + __expf(fmaf(acc[mi][1][r], 64.0f, -64.0f))
                    + __expf(fmaf(acc[mi][2][r], 64.0f, -64.0f))
                    + __expf(fmaf(acc[mi][3][r], 64.0f, -64.0f));
            #pragma unroll
            for (int k = 1; k < 16; k <<= 1) s += __shfl_xor(s, k);
            if (l15 == 0) red[(wm * 64 + mi * 16 + uhi * 4 + r) * 2 + wn] = s;
        }
    }
    __syncthreads();
    if (tid < 128)
        ps[(size_t)ntile * B_ROWS + mtile * 128 + tid] = red[tid * 2] + red[tid * 2 + 1];
}

// ---------- pass 3: per-row sum of partials + exact margin/pad correction
__global__ __launch_bounds__(256) void finalize(
    const float* __restrict__ ps,
    const uint8_t* __restrict__ fb, const uint8_t* __restrict__ wb,
    const int* __restrict__ labels, float* __restrict__ row_loss)
{
    const int row = blockIdx.x;
    const int t   = threadIdx.x;      // 256
    const int lab = labels[row];

    // target logit from the SAME fp8 values the GEMM consumed (consistent cancellation)
    const uint8_t* frow = fb + (size_t)row * DIM;
    const uint8_t* wrow = wb + (size_t)lab * DIM;
    uint32_t fa = *reinterpret_cast<const uint16_t*>(frow + 2 * t);
    uint32_t wa = *reinterpret_cast<const uint16_t*>(wrow + 2 * t);
    float d = fp82f(fa & 0xffu) * fp82f(wa & 0xffu)
            + fp82f(fa >> 8)    * fp82f(wa >> 8);
    #pragma unroll
    for (int k = 1; k < 64; k <<= 1) d += __shfl_xor(d, k);

    float s = 0.0f;
    for (int i = t; i < NT; i += 256) s += ps[(size_t)i * B_ROWS + row];
    #pragma unroll
    for (int k = 1; k < 64; k <<= 1) s += __shfl_xor(s, k);

    __shared__ float sd[4], ssm[4];
    if ((t & 63) == 0) { sd[t >> 6] = d; ssm[t >> 6] = s; }
    __syncthreads();
    if (t == 0) {
        const float dt = sd[0] + sd[1] + sd[2] + sd[3];
        float S = ssm[0] + ssm[1] + ssm[2] + ssm[3];
        const float lt = 64.0f * dt;
        // swap unmargined target term for margined one; remove pad columns (logit 0)
        S += expf(lt - 96.0f) - expf(lt - 64.0f) - (float)NPAD * expf(-64.0f);
        row_loss[row] = 64.0f + logf(S) - (lt - 32.0f);
    }
}

// ---------- pass 4: mean over rows
__global__ __launch_bounds__(256) void mean_k(const float* __restrict__ rl, float* __restrict__ out)
{
    const int t = threadIdx.x;
    float s = 0.0f;
    for (int i = t; i < B_ROWS; i += 256) s += rl[i];
    #pragma unroll
    for (int k = 1; k < 64; k <<= 1) s += __shfl_xor(s, k);
    __shared__ float r4[4];
    if ((t & 63) == 0) r4[t >> 6] = s;
    __syncthreads();
    if (t == 0) out[0] = (r4[0] + r4[1] + r4[2] + r4[3]) * (1.0f / B_ROWS);
}

extern "C" void kernel_launch(void* const* d_in, const int* in_sizes, int n_in,
                              void* d_out, int out_size, void* d_ws, size_t ws_size,
                              hipStream_t stream)
{
    const float* features = (const float*)d_in[0];
    const int*   labels   = (const int*)d_in[1];
    const float* weight   = (const float*)d_in[2];

    char* ws = (char*)d_ws;
    uint8_t* wb = (uint8_t*)ws;                                          // C_PAD * DIM fp8
    uint8_t* fb = (uint8_t*)(ws + (size_t)C_PAD * DIM);                  // B_ROWS * DIM fp8
    float*   psum = (float*)(ws + (size_t)C_PAD * DIM + (size_t)B_ROWS * DIM);
    float*   rl = psum + (size_t)NT * B_ROWS;

    normalize_rows<<<C_PAD / 4, 256, 0, stream>>>(weight, wb, C_CLS, C_PAD);
    normalize_rows<<<B_ROWS / 4, 256, 0, stream>>>(features, fb, B_ROWS, B_ROWS);
    gemm_lse<<<NT * MT, 256, 0, stream>>>(fb, wb, psum);
    finalize<<<B_ROWS, 256, 0, stream>>>(psum, fb, wb, labels, rl);
    mean_k<<<1, 256, 0, stream>>>(rl, (float*)d_out);
}